// Round 8
// baseline (153.507 us; speedup 1.0000x reference)
//
#include <hip/hip_runtime.h>
#include <hip/hip_bf16.h>

// out[b, l, c] = data[(cycle_index[b] % CYC + l) % CYC, c]
// B=4096, L=720, C=64 fp32. ~755MB streaming writes -> write-BW bound.
// R8: R6's chunk-interleaved ordering (the win: grid-wide contiguous
// sliding write window) + LDS-staged table (43KB > 32KB L1 thrashed; LDS
// read frees the vmem pipe to be store-only, like the 6.7TB/s fill).
// Grid=768 (3 blocks/CU at 43KB LDS) so ALL blocks stay resident and the
// window stays contiguous (768 chunks x 4KB = 3MB).

typedef float f4_t __attribute__((ext_vector_type(4)));

#define B_      4096
#define L_      720
#define C4_     16        // 64 floats / 4
#define CYC_    168
#define LPB_    16        // l-values per chunk
#define CHUNKS_ (L_ / LPB_)          // 45 (exact)
#define NCHUNK_ (B_ * CHUNKS_)       // 184320
#define TBLSZ_  (CYC_ * C4_)         // 2688 float4 = 43008 B

__global__ __launch_bounds__(256) void rc_kernel_lds(
    const int* __restrict__ cycle_index,
    const f4_t* __restrict__ data4,    // [CYC][C4]
    f4_t* __restrict__ out4)           // [B][L][C4]
{
    __shared__ f4_t tbl[TBLSZ_];       // 43KB -> 3 blocks/CU

    const int t    = threadIdx.x;
    const int lofs = t >> 4;            // 0..15
    const int c4   = t & 15;            // 0..15

    // Stage the whole table once per block (L2-resident source).
    for (int i = t; i < TBLSZ_; i += 256)
        tbl[i] = data4[i];
    __syncthreads();

    for (int chunk = blockIdx.x; chunk < NCHUNK_; chunk += gridDim.x) {
        const int b  = chunk / CHUNKS_;          // uniform -> scalar path
        const int lc = chunk - b * CHUNKS_;
        const int l  = lc * LPB_ + lofs;

        const int start = cycle_index[b] % CYC_; // uniform scalar load
        int src = start + l;                     // < CYC_ + L_
        src %= CYC_;                             // magic-mul

        const f4_t v = tbl[src * C4_ + c4];      // ds_read_b128
        out4[((size_t)b * L_ + l) * C4_ + c4] = v;   // plain store via L2
    }
}

// Generic fallback (any B/L): R6 structure, vmem loads, plain stores.
__global__ __launch_bounds__(256) void rc_kernel_generic(
    const int* __restrict__ cycle_index,
    const f4_t* __restrict__ data4,
    f4_t* __restrict__ out4,
    int L, int chunks, int nchunk_total)
{
    const int t    = threadIdx.x;
    const int lofs = t >> 4;
    const int c4   = t & 15;

    for (int chunk = blockIdx.x; chunk < nchunk_total; chunk += gridDim.x) {
        const int b  = chunk / chunks;
        const int lc = chunk - b * chunks;
        const int l  = lc * LPB_ + lofs;
        if (l >= L) continue;

        const int start = cycle_index[b] % CYC_;
        int src = start + l;
        src %= CYC_;

        const f4_t v = data4[src * C4_ + c4];
        out4[((size_t)b * (size_t)L + l) * C4_ + c4] = v;
    }
}

extern "C" void kernel_launch(void* const* d_in, const int* in_sizes, int n_in,
                              void* d_out, int out_size, void* d_ws, size_t ws_size,
                              hipStream_t stream) {
    const int*   cycle_index = (const int*)d_in[0];
    const float* data        = (const float*)d_in[2];

    const int B = in_sizes[0];
    const int L = out_size / (B * 64);

    if (B == B_ && L == L_) {
        const int grid = 768;   // 3 blocks/CU x 256 CU: all resident,
                                // contiguous 3MB sliding write window
        rc_kernel_lds<<<grid, 256, 0, stream>>>(
            cycle_index, (const f4_t*)data, (f4_t*)d_out);
    } else {
        const int chunks = (L + LPB_ - 1) / LPB_;
        const int nchunk = B * chunks;
        rc_kernel_generic<<<2048, 256, 0, stream>>>(
            cycle_index, (const f4_t*)data, (f4_t*)d_out,
            L, chunks, nchunk);
    }
}

// Round 9
// 146.053 us; speedup vs baseline: 1.0510x; 1.0510x over previous
//
#include <hip/hip_runtime.h>
#include <hip/hip_bf16.h>

// out[b, l, c] = data[(cycle_index[b] % CYC + l) % CYC, c]
// B=4096, L=720, C=64 fp32. ~755MB streaming writes -> write-BW bound.
// R9: R6 (champion, 120.1us / 6.29 TB/s) + 2-chunk unroll: each block-iter
// handles adjacent chunks 2p and 2p+1 (8KB contiguous), doubling the
// independent store pairs in flight per wave. Ordering unchanged: grid-wide
// contiguous sliding window (2048 blocks x 8KB = 16MB). Plain stores via L2
// (NT proved 25% slower). No LDS (R8 proved slower).

typedef float f4_t __attribute__((ext_vector_type(4)));

#define B_      4096
#define L_      720
#define C4_     16        // 64 floats / 4
#define CYC_    168
#define LPB_    16        // l-values per chunk
#define CHUNKS_ (L_ / LPB_)          // 45 (exact)
#define NCHUNK_ (B_ * CHUNKS_)       // 184320
#define NPAIR_  (NCHUNK_ / 2)        // 92160

__global__ __launch_bounds__(256) void rc_kernel_fixed(
    const int* __restrict__ cycle_index,
    const f4_t* __restrict__ data4,    // [CYC][C4]
    f4_t* __restrict__ out4)           // [B][L][C4]
{
    const int t    = threadIdx.x;
    const int lofs = t >> 4;            // 0..15
    const int c4   = t & 15;            // 0..15

    for (int p = blockIdx.x; p < NPAIR_; p += gridDim.x) {
        #pragma unroll
        for (int u = 0; u < 2; ++u) {
            const int chunk = 2 * p + u;
            const int b  = chunk / CHUNKS_;          // magic-mul
            const int lc = chunk - b * CHUNKS_;
            const int l  = lc * LPB_ + lofs;

            const int start = cycle_index[b] % CYC_; // uniform scalar load
            int src = start + l;                     // < CYC_ + L_
            src %= CYC_;                             // magic-mul

            const f4_t v = data4[src * C4_ + c4];    // L1/L2 table load
            out4[((size_t)b * L_ + l) * C4_ + c4] = v;  // plain store via L2
        }
    }
}

// Generic fallback (any B/L): R6 structure, plain stores.
__global__ __launch_bounds__(256) void rc_kernel_generic(
    const int* __restrict__ cycle_index,
    const f4_t* __restrict__ data4,
    f4_t* __restrict__ out4,
    int L, int chunks, int nchunk_total)
{
    const int t    = threadIdx.x;
    const int lofs = t >> 4;
    const int c4   = t & 15;

    for (int chunk = blockIdx.x; chunk < nchunk_total; chunk += gridDim.x) {
        const int b  = chunk / chunks;
        const int lc = chunk - b * chunks;
        const int l  = lc * LPB_ + lofs;
        if (l >= L) continue;

        const int start = cycle_index[b] % CYC_;
        int src = start + l;
        src %= CYC_;

        const f4_t v = data4[src * C4_ + c4];
        out4[((size_t)b * (size_t)L + l) * C4_ + c4] = v;
    }
}

extern "C" void kernel_launch(void* const* d_in, const int* in_sizes, int n_in,
                              void* d_out, int out_size, void* d_ws, size_t ws_size,
                              hipStream_t stream) {
    const int*   cycle_index = (const int*)d_in[0];
    const float* data        = (const float*)d_in[2];

    const int B = in_sizes[0];
    const int L = out_size / (B * 64);

    const int grid = 2048;  // all resident; 16MB sliding write window

    if (B == B_ && L == L_) {
        rc_kernel_fixed<<<grid, 256, 0, stream>>>(
            cycle_index, (const f4_t*)data, (f4_t*)d_out);
    } else {
        const int chunks = (L + LPB_ - 1) / LPB_;
        const int nchunk = B * chunks;
        rc_kernel_generic<<<2048, 256, 0, stream>>>(
            cycle_index, (const f4_t*)data, (f4_t*)d_out,
            L, chunks, nchunk);
    }
}

// Round 10
// 120.094 us; speedup vs baseline: 1.2782x; 1.2162x over previous
//
#include <hip/hip_runtime.h>
#include <hip/hip_bf16.h>

// out[b, l, c] = data[(cycle_index[b] % CYC + l) % CYC, c]
// B=4096, L=720, C=64 fp32. ~755MB streaming writes -> write-BW bound.
// R10: pure revert to R6 champion (120.1us, 6.29 TB/s).
// Proven invariants (R1-R9 ledger):
//  - chunk-interleaved grid-stride: consecutive blocks write consecutive
//    4KB chunks -> grid-wide contiguous ~8MB sliding write window
//    (per-b streams: -22% R7; strided unroll: -18% R9; grid=768: -22% R8)
//  - PLAIN stores through L2 (nontemporal caps at ~5 TB/s: R3/R5 vs R6)
//  - in-loop vmem table load is free (reg-preload R5/R7 and LDS R8 both lost)
//  - 2048 blocks x 256 threads, all resident

typedef float f4_t __attribute__((ext_vector_type(4)));

#define B_      4096
#define L_      720
#define C4_     16        // 64 floats / 4
#define CYC_    168
#define LPB_    16        // l-values per chunk
#define CHUNKS_ (L_ / LPB_)          // 45 (exact)
#define NCHUNK_ (B_ * CHUNKS_)       // 184320

__global__ __launch_bounds__(256) void rc_kernel_fixed(
    const int* __restrict__ cycle_index,
    const f4_t* __restrict__ data4,    // [CYC][C4]
    f4_t* __restrict__ out4)           // [B][L][C4]
{
    const int t    = threadIdx.x;
    const int lofs = t >> 4;            // 0..15
    const int c4   = t & 15;            // 0..15

    for (int chunk = blockIdx.x; chunk < NCHUNK_; chunk += gridDim.x) {
        const int b  = chunk / CHUNKS_;          // const divisor -> magic mul
        const int lc = chunk - b * CHUNKS_;
        const int l  = lc * LPB_ + lofs;

        const int start = cycle_index[b] % CYC_; // uniform per iteration
        int src = start + l;                     // < CYC_ + L_
        src %= CYC_;                             // const divisor -> magic mul

        const f4_t v = data4[src * C4_ + c4];    // L1/L2-resident 43KB table
        out4[((size_t)b * L_ + l) * C4_ + c4] = v;   // PLAIN store (through L2)
    }
}

// Generic fallback (any B/L), grid-stride, plain stores.
__global__ __launch_bounds__(256) void rc_kernel_generic(
    const int* __restrict__ cycle_index,
    const f4_t* __restrict__ data4,
    f4_t* __restrict__ out4,
    int L, int chunks, int nchunk_total)
{
    const int t    = threadIdx.x;
    const int lofs = t >> 4;
    const int c4   = t & 15;

    for (int chunk = blockIdx.x; chunk < nchunk_total; chunk += gridDim.x) {
        const int b  = chunk / chunks;
        const int lc = chunk - b * chunks;
        const int l  = lc * LPB_ + lofs;
        if (l >= L) continue;

        const int start = cycle_index[b] % CYC_;
        int src = start + l;
        src %= CYC_;

        const f4_t v = data4[src * C4_ + c4];
        out4[((size_t)b * (size_t)L + l) * C4_ + c4] = v;
    }
}

extern "C" void kernel_launch(void* const* d_in, const int* in_sizes, int n_in,
                              void* d_out, int out_size, void* d_ws, size_t ws_size,
                              hipStream_t stream) {
    const int*   cycle_index = (const int*)d_in[0];
    const float* data        = (const float*)d_in[2];

    const int B = in_sizes[0];
    const int L = out_size / (B * 64);

    const int grid = 2048;  // 256 CU x 8 blocks, grid-stride

    if (B == B_ && L == L_) {
        rc_kernel_fixed<<<grid, 256, 0, stream>>>(
            cycle_index, (const f4_t*)data, (f4_t*)d_out);
    } else {
        const int chunks = (L + LPB_ - 1) / LPB_;
        const int nchunk = B * chunks;
        rc_kernel_generic<<<2048, 256, 0, stream>>>(
            cycle_index, (const f4_t*)data, (f4_t*)d_out,
            L, chunks, nchunk);
    }
}